// Round 1
// baseline (93.048 us; speedup 1.0000x reference)
//
#include <hip/hip_runtime.h>
#include <math.h>

// QuGCN pipeline v18 = v17 +
//   K1: fused 2-qubit cross-wave exchange for M-block bits {7,6}
//       (one store+barrier+3 loads instead of two store+barrier+load rounds;
//        barriers per thread 16 -> 10).
//   K2: register-prefetch pipeline (next k-tile's global loads issued before
//       this tile's barrier -> cross-XCD load latency overlaps compute).
//   K3 eval3 unchanged [R12/R16 verbatim].

namespace {

constexpr int NSAMP = 4096;
constexpr int NW_L  = 132;

// ---------- compile-time trig ----------
constexpr double PI_D   = 3.14159265358979323846264338327950288;
constexpr double TWO_PI = 6.28318530717958647692528676655900577;

constexpr double red_pm_pi(double x) {
  double k = x / TWO_PI;
  long long ki = (long long)k;
  double r = x - (double)ki * TWO_PI;
  if (r > PI_D)  r -= TWO_PI;
  if (r < -PI_D) r += TWO_PI;
  return r;
}
constexpr double csin(double x) {
  double r = red_pm_pi(x), r2 = r * r, term = r, sum = r;
  for (int n = 1; n <= 13; ++n) { term *= -r2 / (double)((2*n)*(2*n+1)); sum += term; }
  return sum;
}
constexpr double ccos(double x) {
  double r = red_pm_pi(x), r2 = r * r, term = 1.0, sum = 1.0;
  for (int n = 1; n <= 13; ++n) { term *= -r2 / (double)((2*n-1)*(2*n)); sum += term; }
  return sum;
}

constexpr int PC[28] = {0,1,2,3,4,5,6, 0,1,2,3,4,5, 0,1,2,3,4, 0,1,2,3, 0,1,2, 0,1, 0};
constexpr int PT[28] = {1,2,3,4,5,6,7, 2,3,4,5,6,7, 3,4,5,6,7, 4,5,6,7, 5,6,7, 6,7, 7};

struct Tbl28 { float c[28]; float s[28]; };
constexpr Tbl28 mk_tbl(int base) {
  Tbl28 t{};
  for (int i = 0; i < 28; ++i) {
    double a = 0.5 * (double)(base + i);
    t.c[i] = (float)ccos(a);
    t.s[i] = (float)csin(a);
  }
  return t;
}
constexpr Tbl28 T_CRY = mk_tbl(8);
constexpr Tbl28 T_CRX = mk_tbl(52);

struct DTbl { float v[512]; };
constexpr DTbl mk_dcrz() {
  DTbl t{};
  for (int s = 0; s < 256; ++s) {
    double psi = 0.0;
    for (int i = 0; i < 28; ++i) {
      const int pc = 7 - PC[i], pt = 7 - PT[i];
      if ((s >> pc) & 1) {
        const double half = 0.5 * (double)(96 + i);
        psi += ((s >> pt) & 1) ? half : -half;
      }
    }
    t.v[2*s]   = (float)ccos(psi);
    t.v[2*s+1] = (float)csin(psi);
  }
  return t;
}
__device__ constexpr DTbl D_CRZ = mk_dcrz();

// ---------- single-amp cross-lane xor on lane bit p (0..5) [verified R12] ----------
__device__ __forceinline__ float shx1(float v, int p) {
  if (p == 0) {
    int r = __builtin_amdgcn_update_dpp((int)__float_as_uint(v), (int)__float_as_uint(v),
                                        0xB1, 0xF, 0xF, true);
    return __uint_as_float((unsigned)r);
  }
  if (p == 1) {
    int r = __builtin_amdgcn_update_dpp((int)__float_as_uint(v), (int)__float_as_uint(v),
                                        0x4E, 0xF, 0xF, true);
    return __uint_as_float((unsigned)r);
  }
  if (p == 2) return __uint_as_float((unsigned)__builtin_amdgcn_ds_swizzle(
                      (int)__float_as_uint(v), 0x101F));   // xor 4
  if (p == 3) return __uint_as_float((unsigned)__builtin_amdgcn_ds_swizzle(
                      (int)__float_as_uint(v), 0x201F));   // xor 8
  if (p == 4) return __uint_as_float((unsigned)__builtin_amdgcn_ds_swizzle(
                      (int)__float_as_uint(v), 0x401F));   // xor 16
  return __shfl_xor(v, 32, 64);
}

// ---------- single-amp gate appliers [verified R12/R16] ----------
__device__ __forceinline__ void gen_lane(float& ar, float& ai, int s, int p,
                                         float m00r, float m00i, float m01r, float m01i) {
  const int b = (s >> p) & 1;
  const float dr = m00r;
  const float di = b ? -m00i : m00i;
  const float g  = b ? -m01r : m01r;
  const float hh = m01i;
  const float pr = shx1(ar, p);
  const float pi = shx1(ai, p);
  const float mr = ar, mi = ai;
  ar = dr*mr - di*mi + g*pr - hh*pi;
  ai = dr*mi + di*mr + g*pi + hh*pr;
}

// Fused two-qubit update for gates A on state bit 7 then B on state bit 6
// (both cross-wave). amp'(s) = Bd*Ad*amp(s) + Bd*Ao*amp(s^0x80)
//                            + Bo*Ad*amp(s^0x40) + Bo*Ao*amp(s^0xC0),
// with Ad/Ao chosen by bit7(s), Bd/Bo by bit6(s), same SU(2) sign rules
// as gen_xw (off-diag real flips with bit, off-diag imag does not).
__device__ __forceinline__ void gen_xw2(float& ar, float& ai, int s,
                                        float4 mA, float4 mB, float2* buf) {
  buf[s] = make_float2(ar, ai);
  const int b7 = (s >> 7) & 1;
  const int b6 = (s >> 6) & 1;
  const float Adr = mA.x,               Adi = b7 ? -mA.y : mA.y;
  const float Aor = b7 ? -mA.z : mA.z,  Aoi = mA.w;
  const float Bdr = mB.x,               Bdi = b6 ? -mB.y : mB.y;
  const float Bor = b6 ? -mB.z : mB.z,  Boi = mB.w;
  const float c00r = Adr*Bdr - Adi*Bdi, c00i = Adr*Bdi + Adi*Bdr;
  const float c01r = Aor*Bdr - Aoi*Bdi, c01i = Aor*Bdi + Aoi*Bdr;
  const float c10r = Adr*Bor - Adi*Boi, c10i = Adr*Boi + Adi*Bor;
  const float c11r = Aor*Bor - Aoi*Boi, c11i = Aor*Boi + Aoi*Bor;
  __syncthreads();
  const float2 p7 = buf[s ^ 0x80];
  const float2 p6 = buf[s ^ 0x40];
  const float2 pB = buf[s ^ 0xC0];
  const float mr = ar, mi = ai;
  float nr = c00r*mr - c00i*mi;
  float ni = c00r*mi + c00i*mr;
  nr = fmaf(c01r, p7.x, nr); nr = fmaf(-c01i, p7.y, nr);
  ni = fmaf(c01r, p7.y, ni); ni = fmaf( c01i, p7.x, ni);
  nr = fmaf(c10r, p6.x, nr); nr = fmaf(-c10i, p6.y, nr);
  ni = fmaf(c10r, p6.y, ni); ni = fmaf( c10i, p6.x, ni);
  nr = fmaf(c11r, pB.x, nr); nr = fmaf(-c11i, pB.y, nr);
  ni = fmaf(c11r, pB.y, ni); ni = fmaf( c11i, pB.x, ni);
  ar = nr; ai = ni;
}

__device__ __forceinline__ void cry_lane(float& ar, float& ai, int s, int pc, int pt,
                                         float cc, float sc) {
  const int ctrl = (s >> pc) & 1;
  const float ce = ctrl ? cc : 1.0f;
  float se = ((s >> pt) & 1) ? sc : -sc;
  se = ctrl ? se : 0.0f;
  const float pr = shx1(ar, pt);
  const float pi = shx1(ai, pt);
  ar = ce*ar + se*pr;
  ai = ce*ai + se*pi;
}
__device__ __forceinline__ void cry_xw(float& ar, float& ai, int s, int pc, int pt,
                                       float cc, float sc, float2* buf) {
  buf[s] = make_float2(ar, ai);
  __syncthreads();
  const float2 p = buf[s ^ (1 << pt)];
  const int ctrl = (s >> pc) & 1;
  const float ce = ctrl ? cc : 1.0f;
  float se = ((s >> pt) & 1) ? sc : -sc;
  se = ctrl ? se : 0.0f;
  ar = ce*ar + se*p.x;
  ai = ce*ai + se*p.y;
}
__device__ __forceinline__ void crx_lane(float& ar, float& ai, int s, int pc, int pt,
                                         float cc, float sc) {
  const int ctrl = (s >> pc) & 1;
  const float ce = ctrl ? cc : 1.0f;
  const float se = ctrl ? sc : 0.0f;
  const float pr = shx1(ar, pt);
  const float pi = shx1(ai, pt);
  ar = ce*ar + se*pi;
  ai = ce*ai - se*pr;
}
__device__ __forceinline__ void crx_xw(float& ar, float& ai, int s, int pc, int pt,
                                       float cc, float sc, float2* buf) {
  buf[s] = make_float2(ar, ai);
  __syncthreads();
  const float2 p = buf[s ^ (1 << pt)];
  const int ctrl = (s >> pc) & 1;
  const float ce = ctrl ? cc : 1.0f;
  const float se = ctrl ? sc : 0.0f;
  ar = ce*ar + se*p.y;
  ai = ce*ai - se*p.x;
}

__device__ __forceinline__ unsigned short f2bf(float f) {
  unsigned int u = __float_as_uint(f);
  u = (u + 0x7FFFu + ((u >> 16) & 1u)) >> 16;
  return (unsigned short)u;
}

typedef __attribute__((ext_vector_type(8))) short bf16x8;
typedef __attribute__((ext_vector_type(4))) float f32x4;

} // namespace

// ---------------- K1: build half-circuit unitaries, 4 waves per state ----------------
__global__ __launch_bounds__(256) void build_half4w(const float* __restrict__ qw,
                                                    float* __restrict__ U1c,
                                                    float* __restrict__ U2c) {
  __shared__ float4 sM[48];
  __shared__ float2 xb[2][256];
  const int tid = threadIdx.x;
  const int h   = blockIdx.x >> 8;
  const int s0  = blockIdx.x & 255;
  const int s   = tid;

  if (tid < 48) {
    const int lp  = tid / 24;
    const int rem = tid - lp * 24;
    const int j   = rem >> 3;
    const int q   = rem & 7;
    const int l   = 2 * h + lp;
    float a, bb;
    if (j == 0) {        // M0 = RY(qw[l][q]) * RZ(qw[l-1][124+q])
      a  = qw[l * NW_L + q];
      bb = (l > 0) ? qw[(l - 1) * NW_L + 124 + q] : 0.f;
    } else if (j == 1) { // M1 = RX(44+q) * RY(36+q)
      a  = qw[l * NW_L + 44 + q];
      bb = qw[l * NW_L + 36 + q];
    } else {             // M2 = RZ(88+q) * RX(80+q); RZ dropped at l=3
      a  = (l < 3) ? qw[l * NW_L + 88 + q] : 0.f;
      bb = qw[l * NW_L + 80 + q];
    }
    float sa, ca, sb, cb;
    __sincosf(0.5f * a,  &sa, &ca);
    __sincosf(0.5f * bb, &sb, &cb);
    float4 m;
    if (j == 0)      m = make_float4(ca*cb, -ca*sb, -sa*cb, -sa*sb); // RY*RZ
    else if (j == 1) m = make_float4(ca*cb, -sa*sb, -ca*sb, -sa*cb); // RX*RY
    else             m = make_float4(ca*cb, -sa*cb, -sb*sa, -sb*ca); // RZ*RX
    sM[tid] = m;
  }

  float ar = (s == s0) ? 1.f : 0.f;
  float ai = 0.f;
  const float dzr = D_CRZ.v[2*s];
  const float dzi = D_CRZ.v[2*s+1];
  __syncthreads();

  int pb = 0;
#pragma unroll 1
  for (int lp = 0; lp < 2; ++lp) {
    const int base = lp * 24;
    // M0 block: bits 7,6 fused cross-wave; bits 5..0 in-wave
    {
      gen_xw2(ar, ai, s, sM[base + 0], sM[base + 1], xb[pb]); pb ^= 1;
#pragma unroll
      for (int q = 2; q < 8; ++q) {
        float4 m = sM[base + q];
        gen_lane(ar, ai, s, 7 - q, m.x, m.y, m.z, m.w);
      }
    }
    // CRY block
#pragma unroll
    for (int i = 0; i < 28; ++i) {
      const int pc = 7 - PC[i], pt = 7 - PT[i];
      const float cc = T_CRY.c[i], sc = T_CRY.s[i];
      if (pt == 6) { cry_xw(ar, ai, s, pc, pt, cc, sc, xb[pb]); pb ^= 1; }
      else         cry_lane(ar, ai, s, pc, pt, cc, sc);
    }
    // M1 block
    {
      gen_xw2(ar, ai, s, sM[base + 8], sM[base + 9], xb[pb]); pb ^= 1;
#pragma unroll
      for (int q = 2; q < 8; ++q) {
        float4 m = sM[base + 8 + q];
        gen_lane(ar, ai, s, 7 - q, m.x, m.y, m.z, m.w);
      }
    }
    // CRX block
#pragma unroll
    for (int i = 0; i < 28; ++i) {
      const int pc = 7 - PC[i], pt = 7 - PT[i];
      const float cc = T_CRX.c[i], sc = T_CRX.s[i];
      if (pt == 6) { crx_xw(ar, ai, s, pc, pt, cc, sc, xb[pb]); pb ^= 1; }
      else         crx_lane(ar, ai, s, pc, pt, cc, sc);
    }
    // M2 block
    {
      gen_xw2(ar, ai, s, sM[base + 16], sM[base + 17], xb[pb]); pb ^= 1;
#pragma unroll
      for (int q = 2; q < 8; ++q) {
        float4 m = sM[base + 16 + q];
        gen_lane(ar, ai, s, 7 - q, m.x, m.y, m.z, m.w);
      }
    }
    // CRZ diagonal (dropped at l==3)
    if (2 * h + lp < 3) {
      const float mr = ar, mi = ai;
      ar = mr*dzr - mi*dzi;
      ai = mr*dzi + mi*dzr;
    }
  }

  float* Uc = h ? U2c : U1c;
  ((float2*)(Uc + (size_t)s0 * 512))[s] = make_float2(ar, ai);
}

// ---------------- K2: U = U2 * U1 (complex), emit bf16 — reg-prefetch pipeline ----------------
__global__ __launch_bounds__(256) void combine_u(const float* __restrict__ U1c,
                                                 const float* __restrict__ U2c,
                                                 unsigned short* __restrict__ Ubf) {
  __shared__ float2 S2[2][32 * 16];   // [buf][kk][i]
  __shared__ float2 S1[2][16 * 33];   // [buf][j][kk] padded
  const int tid = threadIdx.x;
  const int ti  = tid & 15;
  const int tj  = tid >> 4;
  const int bi  = blockIdx.x & 15;
  const int bj  = blockIdx.x >> 4;

  // per-thread staging coordinates (two elements each for S2 and S1)
  const int s0_ = tid,        s1_ = 256 + tid;
  const int k0  = s0_ >> 4,   i0  = s0_ & 15;
  const int k1  = s1_ >> 4,   i1  = s1_ & 15;
  const int j20 = s0_ >> 5,   k20 = s0_ & 31;
  const int j21 = s1_ >> 5,   k21 = s1_ & 31;

  // prefetch tile 0 into registers
  float2 r2a = *(const float2*)(U2c + (size_t)(k0) * 512 + (bi*16 + i0) * 2);
  float2 r2b = *(const float2*)(U2c + (size_t)(k1) * 512 + (bi*16 + i1) * 2);
  float2 r1a = *(const float2*)(U1c + (size_t)(bj*16 + j20) * 512 + (k20) * 2);
  float2 r1b = *(const float2*)(U1c + (size_t)(bj*16 + j21) * 512 + (k21) * 2);

  float accr = 0.f, acci = 0.f;
#pragma unroll 1
  for (int kt = 0; kt < 8; ++kt) {
    const int buf = kt & 1;
    // commit prefetched tile kt to LDS (buf reuse ordered by barrier kt-1:
    // reads of buf at kt-2 precede barrier(kt-1), which precedes these stores)
    S2[buf][k0 * 16 + i0]  = r2a;
    S2[buf][k1 * 16 + i1]  = r2b;
    S1[buf][j20 * 33 + k20] = r1a;
    S1[buf][j21 * 33 + k21] = r1b;
    // issue next tile's global loads NOW so their latency overlaps compute
    if (kt < 7) {
      const int kn = (kt + 1) * 32;
      r2a = *(const float2*)(U2c + (size_t)(kn + k0) * 512 + (bi*16 + i0) * 2);
      r2b = *(const float2*)(U2c + (size_t)(kn + k1) * 512 + (bi*16 + i1) * 2);
      r1a = *(const float2*)(U1c + (size_t)(bj*16 + j20) * 512 + (kn + k20) * 2);
      r1b = *(const float2*)(U1c + (size_t)(bj*16 + j21) * 512 + (kn + k21) * 2);
    }
    __syncthreads();
#pragma unroll
    for (int kk = 0; kk < 32; ++kk) {
      const float2 a = S2[buf][kk * 16 + ti];
      const float2 b = S1[buf][tj * 33 + kk];
      accr = fmaf(a.x, b.x, accr);  accr = fmaf(-a.y, b.y, accr);
      acci = fmaf(a.x, b.y, acci);  acci = fmaf(a.y, b.x, acci);
    }
  }
  const int i = bi * 16 + ti, j = bj * 16 + tj;
  Ubf[(size_t)i * 256 + j]         = f2bf(accr);
  Ubf[(size_t)(i + 256) * 256 + j] = f2bf(acci);
}

// ---------------- K3: eval3 — 16 waves/block, 32 rows/wave [R12/R16 verbatim] ----------------
__global__ __launch_bounds__(1024) void eval3(const float* __restrict__ x,
                                              const unsigned short* __restrict__ Ubf,
                                              const float* __restrict__ fcw,
                                              const float* __restrict__ fcb,
                                              float* __restrict__ out) {
  __shared__ unsigned short Xs[16 * 264];   // [col][k] bf16, padded
  __shared__ float Zp[16][16][9];           // [wave][col][9]
  __shared__ float Zf[16][9];
  const int tid  = threadIdx.x;
  const int lane = tid & 63;
  const int w    = tid >> 6;                // 0..15
  const int colbase = blockIdx.x * 16;

  {
    const int k  = tid >> 2;
    const int c4 = (tid & 3) * 4;
    const float4 v = *(const float4*)(x + (size_t)k * NSAMP + colbase + c4);
    Xs[(c4 + 0) * 264 + k] = f2bf(v.x);
    Xs[(c4 + 1) * 264 + k] = f2bf(v.y);
    Xs[(c4 + 2) * 264 + k] = f2bf(v.z);
    Xs[(c4 + 3) * 264 + k] = f2bf(v.w);
  }
  __syncthreads();

  const int quad = lane >> 4;
  const int n    = lane & 15;
  const int rowb = w * 32;

  f32x4 acc[2];
  acc[0] = (f32x4){0.f, 0.f, 0.f, 0.f};
  acc[1] = (f32x4){0.f, 0.f, 0.f, 0.f};

#pragma unroll
  for (int kt = 0; kt < 8; ++kt) {
    const bf16x8 bfrag = *(const bf16x8*)&Xs[n * 264 + kt * 32 + quad * 8];
#pragma unroll
    for (int rt = 0; rt < 2; ++rt) {
      const int row = rowb + rt * 16 + n;
      const bf16x8 afrag = *(const bf16x8*)(Ubf + (size_t)row * 256 + kt * 32 + quad * 8);
      acc[rt] = __builtin_amdgcn_mfma_f32_16x16x32_bf16(afrag, bfrag, acc[rt], 0, 0, 0);
    }
  }

  float za[9];
#pragma unroll
  for (int i = 0; i < 9; ++i) za[i] = 0.f;
  const float m4 = (lane & 32) ? -1.f : 1.f;   // s bit3 = quad bit1
  const float m5 = (lane & 16) ? -1.f : 1.f;   // s bit2 = quad bit0
#pragma unroll
  for (int rt = 0; rt < 2; ++rt) {
#pragma unroll
    for (int reg = 0; reg < 4; ++reg) {
      const float v = acc[rt][reg];
      const float p = v * v;
      za[0] += p;
      za[1] += (w & 4)   ? -p : p;   // q0: s bit7
      za[2] += (w & 2)   ? -p : p;   // q1: s bit6
      za[3] += (w & 1)   ? -p : p;   // q2: s bit5
      za[4] += rt        ? -p : p;   // q3: s bit4
      za[5] = fmaf(m4, p, za[5]);    // q4
      za[6] = fmaf(m5, p, za[6]);    // q5
      za[7] += (reg & 2) ? -p : p;   // q6: s bit1
      za[8] += (reg & 1) ? -p : p;   // q7: s bit0
    }
  }
#pragma unroll
  for (int off = 16; off <= 32; off <<= 1) {
#pragma unroll
    for (int i = 0; i < 9; ++i) za[i] += __shfl_xor(za[i], off, 64);
  }
  if (lane < 16) {
#pragma unroll
    for (int i = 0; i < 9; ++i) Zp[w][lane][i] = za[i];
  }
  __syncthreads();

  if (tid < 144) {
    const int col = tid / 9, q = tid - col * 9;
    float z = 0.f;
#pragma unroll
    for (int ww = 0; ww < 16; ++ww) z += Zp[ww][col][q];
    Zf[col][q] = z;
  }
  __syncthreads();

  if (tid < 112) {
    const int col = tid / 7, oo = tid - col * 7;
    const float inv = 1.f / Zf[col][0];
    float v = fcb[oo];
#pragma unroll
    for (int q = 0; q < 8; ++q)
      v = fmaf(fcw[oo * 8 + q], Zf[col][1 + q] * inv, v);
    out[(size_t)(colbase + col) * 7 + oo] = v;
  }
}

extern "C" void kernel_launch(void* const* d_in, const int* in_sizes, int n_in,
                              void* d_out, int out_size, void* d_ws, size_t ws_size,
                              hipStream_t stream) {
  const float* x   = (const float*)d_in[0];   // [256, 4096]
  const float* qw  = (const float*)d_in[1];   // [4, 132]
  const float* fcw = (const float*)d_in[2];   // [7, 8]
  const float* fcb = (const float*)d_in[3];   // [7]
  float* out = (float*)d_out;                 // [4096, 7]

  float* U1c = (float*)d_ws;                      // 256x256 complex fp32 (512 KB)
  float* U2c = U1c + 256 * 512;                   // 512 KB
  unsigned short* Ubf = (unsigned short*)(U2c + 256 * 512);  // 512x256 bf16 (256 KB)

  hipLaunchKernelGGL(build_half4w, dim3(512), dim3(256),  0, stream, qw, U1c, U2c);
  hipLaunchKernelGGL(combine_u,    dim3(256), dim3(256),  0, stream, U1c, U2c, Ubf);
  hipLaunchKernelGGL(eval3,        dim3(256), dim3(1024), 0, stream, x, Ubf, fcw, fcb, out);
}

// Round 2
// 88.449 us; speedup vs baseline: 1.0520x; 1.0520x over previous
//
#include <hip/hip_runtime.h>
#include <math.h>

// QuGCN pipeline v19 = exact revert to v17 (best verified: 88.6 us).
// R1 post-mortem: (a) K2 reg-prefetch moved global-load latency INTO the
// compiler's pre-barrier vmcnt(0) drain (net loss); (b) K1 fused 2-qubit
// exchange lengthened the post-barrier dependent chain (3 LDS loads + 12 FMA)
// at 2-blocks/SIMD where the saved barrier was already hidden. Both reverted.
//   K1 build_half4w : 512 blk x 256 thr. Block (h,s0) simulates basis e_{s0}
//                     through half h (U = U2*U1). Bits 0..5 in-wave
//                     (DPP / ds_swizzle / shfl); bits 6,7 via double-buffered
//                     LDS exchange (1 barrier each).
//   K2 combine_u    : U = U2*U1 complex GEMM (fp32), emits bf16 [re;im];
//                     k-tiles double-buffered (1 barrier per tile).
//   K3 eval3        : amps = U*x via mfma_f32_16x16x32_bf16, 16 waves/block,
//                     fused |amp|^2 -> <Z_q> -> norm -> head.

namespace {

constexpr int NSAMP = 4096;
constexpr int NW_L  = 132;

// ---------- compile-time trig ----------
constexpr double PI_D   = 3.14159265358979323846264338327950288;
constexpr double TWO_PI = 6.28318530717958647692528676655900577;

constexpr double red_pm_pi(double x) {
  double k = x / TWO_PI;
  long long ki = (long long)k;
  double r = x - (double)ki * TWO_PI;
  if (r > PI_D)  r -= TWO_PI;
  if (r < -PI_D) r += TWO_PI;
  return r;
}
constexpr double csin(double x) {
  double r = red_pm_pi(x), r2 = r * r, term = r, sum = r;
  for (int n = 1; n <= 13; ++n) { term *= -r2 / (double)((2*n)*(2*n+1)); sum += term; }
  return sum;
}
constexpr double ccos(double x) {
  double r = red_pm_pi(x), r2 = r * r, term = 1.0, sum = 1.0;
  for (int n = 1; n <= 13; ++n) { term *= -r2 / (double)((2*n-1)*(2*n)); sum += term; }
  return sum;
}

constexpr int PC[28] = {0,1,2,3,4,5,6, 0,1,2,3,4,5, 0,1,2,3,4, 0,1,2,3, 0,1,2, 0,1, 0};
constexpr int PT[28] = {1,2,3,4,5,6,7, 2,3,4,5,6,7, 3,4,5,6,7, 4,5,6,7, 5,6,7, 6,7, 7};

struct Tbl28 { float c[28]; float s[28]; };
constexpr Tbl28 mk_tbl(int base) {
  Tbl28 t{};
  for (int i = 0; i < 28; ++i) {
    double a = 0.5 * (double)(base + i);
    t.c[i] = (float)ccos(a);
    t.s[i] = (float)csin(a);
  }
  return t;
}
constexpr Tbl28 T_CRY = mk_tbl(8);
constexpr Tbl28 T_CRX = mk_tbl(52);

struct DTbl { float v[512]; };
constexpr DTbl mk_dcrz() {
  DTbl t{};
  for (int s = 0; s < 256; ++s) {
    double psi = 0.0;
    for (int i = 0; i < 28; ++i) {
      const int pc = 7 - PC[i], pt = 7 - PT[i];
      if ((s >> pc) & 1) {
        const double half = 0.5 * (double)(96 + i);
        psi += ((s >> pt) & 1) ? half : -half;
      }
    }
    t.v[2*s]   = (float)ccos(psi);
    t.v[2*s+1] = (float)csin(psi);
  }
  return t;
}
__device__ constexpr DTbl D_CRZ = mk_dcrz();

// ---------- single-amp cross-lane xor on lane bit p (0..5) [verified R12] ----------
__device__ __forceinline__ float shx1(float v, int p) {
  if (p == 0) {
    int r = __builtin_amdgcn_update_dpp((int)__float_as_uint(v), (int)__float_as_uint(v),
                                        0xB1, 0xF, 0xF, true);
    return __uint_as_float((unsigned)r);
  }
  if (p == 1) {
    int r = __builtin_amdgcn_update_dpp((int)__float_as_uint(v), (int)__float_as_uint(v),
                                        0x4E, 0xF, 0xF, true);
    return __uint_as_float((unsigned)r);
  }
  if (p == 2) return __uint_as_float((unsigned)__builtin_amdgcn_ds_swizzle(
                      (int)__float_as_uint(v), 0x101F));   // xor 4
  if (p == 3) return __uint_as_float((unsigned)__builtin_amdgcn_ds_swizzle(
                      (int)__float_as_uint(v), 0x201F));   // xor 8
  if (p == 4) return __uint_as_float((unsigned)__builtin_amdgcn_ds_swizzle(
                      (int)__float_as_uint(v), 0x401F));   // xor 16
  return __shfl_xor(v, 32, 64);
}

// ---------- single-amp gate appliers [verified R12/R16] ----------
__device__ __forceinline__ void gen_lane(float& ar, float& ai, int s, int p,
                                         float m00r, float m00i, float m01r, float m01i) {
  const int b = (s >> p) & 1;
  const float dr = m00r;
  const float di = b ? -m00i : m00i;
  const float g  = b ? -m01r : m01r;
  const float hh = m01i;
  const float pr = shx1(ar, p);
  const float pi = shx1(ai, p);
  const float mr = ar, mi = ai;
  ar = dr*mr - di*mi + g*pr - hh*pi;
  ai = dr*mi + di*mr + g*pi + hh*pr;
}
__device__ __forceinline__ void gen_xw(float& ar, float& ai, int s, int p,
                                       float m00r, float m00i, float m01r, float m01i,
                                       float2* buf) {
  buf[s] = make_float2(ar, ai);
  __syncthreads();
  const float2 pt = buf[s ^ (1 << p)];
  const int b = (s >> p) & 1;
  const float dr = m00r;
  const float di = b ? -m00i : m00i;
  const float g  = b ? -m01r : m01r;
  const float hh = m01i;
  const float mr = ar, mi = ai;
  ar = dr*mr - di*mi + g*pt.x - hh*pt.y;
  ai = dr*mi + di*mr + g*pt.y + hh*pt.x;
}
__device__ __forceinline__ void cry_lane(float& ar, float& ai, int s, int pc, int pt,
                                         float cc, float sc) {
  const int ctrl = (s >> pc) & 1;
  const float ce = ctrl ? cc : 1.0f;
  float se = ((s >> pt) & 1) ? sc : -sc;
  se = ctrl ? se : 0.0f;
  const float pr = shx1(ar, pt);
  const float pi = shx1(ai, pt);
  ar = ce*ar + se*pr;
  ai = ce*ai + se*pi;
}
__device__ __forceinline__ void cry_xw(float& ar, float& ai, int s, int pc, int pt,
                                       float cc, float sc, float2* buf) {
  buf[s] = make_float2(ar, ai);
  __syncthreads();
  const float2 p = buf[s ^ (1 << pt)];
  const int ctrl = (s >> pc) & 1;
  const float ce = ctrl ? cc : 1.0f;
  float se = ((s >> pt) & 1) ? sc : -sc;
  se = ctrl ? se : 0.0f;
  ar = ce*ar + se*p.x;
  ai = ce*ai + se*p.y;
}
__device__ __forceinline__ void crx_lane(float& ar, float& ai, int s, int pc, int pt,
                                         float cc, float sc) {
  const int ctrl = (s >> pc) & 1;
  const float ce = ctrl ? cc : 1.0f;
  const float se = ctrl ? sc : 0.0f;
  const float pr = shx1(ar, pt);
  const float pi = shx1(ai, pt);
  ar = ce*ar + se*pi;
  ai = ce*ai - se*pr;
}
__device__ __forceinline__ void crx_xw(float& ar, float& ai, int s, int pc, int pt,
                                       float cc, float sc, float2* buf) {
  buf[s] = make_float2(ar, ai);
  __syncthreads();
  const float2 p = buf[s ^ (1 << pt)];
  const int ctrl = (s >> pc) & 1;
  const float ce = ctrl ? cc : 1.0f;
  const float se = ctrl ? sc : 0.0f;
  ar = ce*ar + se*p.y;
  ai = ce*ai - se*p.x;
}

__device__ __forceinline__ unsigned short f2bf(float f) {
  unsigned int u = __float_as_uint(f);
  u = (u + 0x7FFFu + ((u >> 16) & 1u)) >> 16;
  return (unsigned short)u;
}

typedef __attribute__((ext_vector_type(8))) short bf16x8;
typedef __attribute__((ext_vector_type(4))) float f32x4;

} // namespace

// ---------------- K1: build half-circuit unitaries, 4 waves per state [R16 verbatim] ----------------
__global__ __launch_bounds__(256) void build_half4w(const float* __restrict__ qw,
                                                    float* __restrict__ U1c,
                                                    float* __restrict__ U2c) {
  __shared__ float4 sM[48];
  __shared__ float2 xb[2][256];
  const int tid = threadIdx.x;
  const int h   = blockIdx.x >> 8;
  const int s0  = blockIdx.x & 255;
  const int s   = tid;

  if (tid < 48) {
    const int lp  = tid / 24;
    const int rem = tid - lp * 24;
    const int j   = rem >> 3;
    const int q   = rem & 7;
    const int l   = 2 * h + lp;
    float a, bb;
    if (j == 0) {        // M0 = RY(qw[l][q]) * RZ(qw[l-1][124+q])
      a  = qw[l * NW_L + q];
      bb = (l > 0) ? qw[(l - 1) * NW_L + 124 + q] : 0.f;
    } else if (j == 1) { // M1 = RX(44+q) * RY(36+q)
      a  = qw[l * NW_L + 44 + q];
      bb = qw[l * NW_L + 36 + q];
    } else {             // M2 = RZ(88+q) * RX(80+q); RZ dropped at l=3
      a  = (l < 3) ? qw[l * NW_L + 88 + q] : 0.f;
      bb = qw[l * NW_L + 80 + q];
    }
    float sa, ca, sb, cb;
    __sincosf(0.5f * a,  &sa, &ca);
    __sincosf(0.5f * bb, &sb, &cb);
    float4 m;
    if (j == 0)      m = make_float4(ca*cb, -ca*sb, -sa*cb, -sa*sb); // RY*RZ
    else if (j == 1) m = make_float4(ca*cb, -sa*sb, -ca*sb, -sa*cb); // RX*RY
    else             m = make_float4(ca*cb, -sa*cb, -sb*sa, -sb*ca); // RZ*RX
    sM[tid] = m;
  }

  float ar = (s == s0) ? 1.f : 0.f;
  float ai = 0.f;
  const float dzr = D_CRZ.v[2*s];
  const float dzi = D_CRZ.v[2*s+1];
  __syncthreads();

  int pb = 0;
#pragma unroll 1
  for (int lp = 0; lp < 2; ++lp) {
    const int base = lp * 24;
    // M0 block
#pragma unroll
    for (int q = 0; q < 8; ++q) {
      float4 m = sM[base + q];
      if (q <= 1) { gen_xw(ar, ai, s, 7 - q, m.x, m.y, m.z, m.w, xb[pb]); pb ^= 1; }
      else        gen_lane(ar, ai, s, 7 - q, m.x, m.y, m.z, m.w);
    }
    // CRY block
#pragma unroll
    for (int i = 0; i < 28; ++i) {
      const int pc = 7 - PC[i], pt = 7 - PT[i];
      const float cc = T_CRY.c[i], sc = T_CRY.s[i];
      if (pt == 6) { cry_xw(ar, ai, s, pc, pt, cc, sc, xb[pb]); pb ^= 1; }
      else         cry_lane(ar, ai, s, pc, pt, cc, sc);
    }
    // M1 block
#pragma unroll
    for (int q = 0; q < 8; ++q) {
      float4 m = sM[base + 8 + q];
      if (q <= 1) { gen_xw(ar, ai, s, 7 - q, m.x, m.y, m.z, m.w, xb[pb]); pb ^= 1; }
      else        gen_lane(ar, ai, s, 7 - q, m.x, m.y, m.z, m.w);
    }
    // CRX block
#pragma unroll
    for (int i = 0; i < 28; ++i) {
      const int pc = 7 - PC[i], pt = 7 - PT[i];
      const float cc = T_CRX.c[i], sc = T_CRX.s[i];
      if (pt == 6) { crx_xw(ar, ai, s, pc, pt, cc, sc, xb[pb]); pb ^= 1; }
      else         crx_lane(ar, ai, s, pc, pt, cc, sc);
    }
    // M2 block
#pragma unroll
    for (int q = 0; q < 8; ++q) {
      float4 m = sM[base + 16 + q];
      if (q <= 1) { gen_xw(ar, ai, s, 7 - q, m.x, m.y, m.z, m.w, xb[pb]); pb ^= 1; }
      else        gen_lane(ar, ai, s, 7 - q, m.x, m.y, m.z, m.w);
    }
    // CRZ diagonal (dropped at l==3)
    if (2 * h + lp < 3) {
      const float mr = ar, mi = ai;
      ar = mr*dzr - mi*dzi;
      ai = mr*dzi + mi*dzr;
    }
  }

  float* Uc = h ? U2c : U1c;
  ((float2*)(Uc + (size_t)s0 * 512))[s] = make_float2(ar, ai);
}

// ---------------- K2: U = U2 * U1 (complex), emit bf16 — double-buffered k-tiles ----------------
__global__ __launch_bounds__(256) void combine_u(const float* __restrict__ U1c,
                                                 const float* __restrict__ U2c,
                                                 unsigned short* __restrict__ Ubf) {
  __shared__ float2 S2[2][32 * 16];   // [buf][kk][i]
  __shared__ float2 S1[2][16 * 33];   // [buf][j][kk] padded
  const int tid = threadIdx.x;
  const int ti  = tid & 15;
  const int tj  = tid >> 4;
  const int bi  = blockIdx.x & 15;
  const int bj  = blockIdx.x >> 4;

  float accr = 0.f, acci = 0.f;
#pragma unroll 1
  for (int kt = 0; kt < 8; ++kt) {
    const int buf = kt & 1;
    // stage this k-tile (reuse of `buf` is ordered by the PREVIOUS tile's
    // barrier two iterations back — reads of buf at kt-2 precede barrier(kt-1),
    // which precedes these stores)
#pragma unroll
    for (int v = 0; v < 2; ++v) {
      const int s = v * 256 + tid;
      const int k  = s >> 4, i = s & 15;
      S2[buf][k * 16 + i] = *(const float2*)(U2c + (size_t)(kt*32 + k) * 512 + (bi*16 + i) * 2);
      const int j2 = s >> 5, k2 = s & 31;
      S1[buf][j2 * 33 + k2] = *(const float2*)(U1c + (size_t)(bj*16 + j2) * 512 + (kt*32 + k2) * 2);
    }
    __syncthreads();
#pragma unroll
    for (int kk = 0; kk < 32; ++kk) {
      const float2 a = S2[buf][kk * 16 + ti];
      const float2 b = S1[buf][tj * 33 + kk];
      accr = fmaf(a.x, b.x, accr);  accr = fmaf(-a.y, b.y, accr);
      acci = fmaf(a.x, b.y, acci);  acci = fmaf(a.y, b.x, acci);
    }
  }
  const int i = bi * 16 + ti, j = bj * 16 + tj;
  Ubf[(size_t)i * 256 + j]         = f2bf(accr);
  Ubf[(size_t)(i + 256) * 256 + j] = f2bf(acci);
}

// ---------------- K3: eval3 — 16 waves/block, 32 rows/wave [R12/R16 verbatim] ----------------
__global__ __launch_bounds__(1024) void eval3(const float* __restrict__ x,
                                              const unsigned short* __restrict__ Ubf,
                                              const float* __restrict__ fcw,
                                              const float* __restrict__ fcb,
                                              float* __restrict__ out) {
  __shared__ unsigned short Xs[16 * 264];   // [col][k] bf16, padded
  __shared__ float Zp[16][16][9];           // [wave][col][9]
  __shared__ float Zf[16][9];
  const int tid  = threadIdx.x;
  const int lane = tid & 63;
  const int w    = tid >> 6;                // 0..15
  const int colbase = blockIdx.x * 16;

  {
    const int k  = tid >> 2;
    const int c4 = (tid & 3) * 4;
    const float4 v = *(const float4*)(x + (size_t)k * NSAMP + colbase + c4);
    Xs[(c4 + 0) * 264 + k] = f2bf(v.x);
    Xs[(c4 + 1) * 264 + k] = f2bf(v.y);
    Xs[(c4 + 2) * 264 + k] = f2bf(v.z);
    Xs[(c4 + 3) * 264 + k] = f2bf(v.w);
  }
  __syncthreads();

  const int quad = lane >> 4;
  const int n    = lane & 15;
  const int rowb = w * 32;

  f32x4 acc[2];
  acc[0] = (f32x4){0.f, 0.f, 0.f, 0.f};
  acc[1] = (f32x4){0.f, 0.f, 0.f, 0.f};

#pragma unroll
  for (int kt = 0; kt < 8; ++kt) {
    const bf16x8 bfrag = *(const bf16x8*)&Xs[n * 264 + kt * 32 + quad * 8];
#pragma unroll
    for (int rt = 0; rt < 2; ++rt) {
      const int row = rowb + rt * 16 + n;
      const bf16x8 afrag = *(const bf16x8*)(Ubf + (size_t)row * 256 + kt * 32 + quad * 8);
      acc[rt] = __builtin_amdgcn_mfma_f32_16x16x32_bf16(afrag, bfrag, acc[rt], 0, 0, 0);
    }
  }

  float za[9];
#pragma unroll
  for (int i = 0; i < 9; ++i) za[i] = 0.f;
  const float m4 = (lane & 32) ? -1.f : 1.f;   // s bit3 = quad bit1
  const float m5 = (lane & 16) ? -1.f : 1.f;   // s bit2 = quad bit0
#pragma unroll
  for (int rt = 0; rt < 2; ++rt) {
#pragma unroll
    for (int reg = 0; reg < 4; ++reg) {
      const float v = acc[rt][reg];
      const float p = v * v;
      za[0] += p;
      za[1] += (w & 4)   ? -p : p;   // q0: s bit7
      za[2] += (w & 2)   ? -p : p;   // q1: s bit6
      za[3] += (w & 1)   ? -p : p;   // q2: s bit5
      za[4] += rt        ? -p : p;   // q3: s bit4
      za[5] = fmaf(m4, p, za[5]);    // q4
      za[6] = fmaf(m5, p, za[6]);    // q5
      za[7] += (reg & 2) ? -p : p;   // q6: s bit1
      za[8] += (reg & 1) ? -p : p;   // q7: s bit0
    }
  }
#pragma unroll
  for (int off = 16; off <= 32; off <<= 1) {
#pragma unroll
    for (int i = 0; i < 9; ++i) za[i] += __shfl_xor(za[i], off, 64);
  }
  if (lane < 16) {
#pragma unroll
    for (int i = 0; i < 9; ++i) Zp[w][lane][i] = za[i];
  }
  __syncthreads();

  if (tid < 144) {
    const int col = tid / 9, q = tid - col * 9;
    float z = 0.f;
#pragma unroll
    for (int ww = 0; ww < 16; ++ww) z += Zp[ww][col][q];
    Zf[col][q] = z;
  }
  __syncthreads();

  if (tid < 112) {
    const int col = tid / 7, oo = tid - col * 7;
    const float inv = 1.f / Zf[col][0];
    float v = fcb[oo];
#pragma unroll
    for (int q = 0; q < 8; ++q)
      v = fmaf(fcw[oo * 8 + q], Zf[col][1 + q] * inv, v);
    out[(size_t)(colbase + col) * 7 + oo] = v;
  }
}

extern "C" void kernel_launch(void* const* d_in, const int* in_sizes, int n_in,
                              void* d_out, int out_size, void* d_ws, size_t ws_size,
                              hipStream_t stream) {
  const float* x   = (const float*)d_in[0];   // [256, 4096]
  const float* qw  = (const float*)d_in[1];   // [4, 132]
  const float* fcw = (const float*)d_in[2];   // [7, 8]
  const float* fcb = (const float*)d_in[3];   // [7]
  float* out = (float*)d_out;                 // [4096, 7]

  float* U1c = (float*)d_ws;                      // 256x256 complex fp32 (512 KB)
  float* U2c = U1c + 256 * 512;                   // 512 KB
  unsigned short* Ubf = (unsigned short*)(U2c + 256 * 512);  // 512x256 bf16 (256 KB)

  hipLaunchKernelGGL(build_half4w, dim3(512), dim3(256),  0, stream, qw, U1c, U2c);
  hipLaunchKernelGGL(combine_u,    dim3(256), dim3(256),  0, stream, U1c, U2c, Ubf);
  hipLaunchKernelGGL(eval3,        dim3(256), dim3(1024), 0, stream, x, Ubf, fcw, fcb, out);
}